// Round 15
// baseline (2135.566 us; speedup 1.0000x reference)
//
#include <hip/hip_runtime.h>
#include <hip/hip_cooperative_groups.h>

namespace cg = cooperative_groups;

#define NN 100000
#define NE 1600000
#define DIM0 11
#define H 128
#define NL 4
#define NG 4096
#define EPS 1e-5f

#define NBKT 391       // buckets of 256 nodes: bucket = dst >> 8
#define CAP 5120       // fixed bucket capacity
#define SUBCAP 1280    // per-64-node sub-region of col
#define EPB 2048       // edges per bscatter work item
static constexpr int NBB = (NE + EPB - 1) / EPB;          // 782
#define PREP_B 32
#define RANGE_B 391
static constexpr int NITEMS_A = PREP_B + RANGE_B + NBB + NN / 16;  // 7455
static constexpr int NITEMS_B = NBKT * 4;                 // 1564
static constexpr int NTILES = (NN + 63) / 64;             // 1563 layer tiles
static constexpr int GRID_MEGA = 1024;                    // 4/CU needed; >=2x headroom

typedef _Float16 f16x8 __attribute__((ext_vector_type(8)));
typedef float f32x4 __attribute__((ext_vector_type(4)));
typedef float f32x2 __attribute__((ext_vector_type(2)));

// r27 post-mortem: absmax 1.0547 == max|ref| -> out stayed zero -> the
// cooperative launch was REJECTED (return code unchecked), not a race.
// r28 (this round), three-way hardening:
//  (1) capacity: grid 1563 -> 1024 + tile-stride (need 4/CU, cap 8/CU);
//  (2) coherence: __threadfence() AFTER each grid.sync too (acquire side);
//  (3) launch check + fallback to the r13-proven multi-kernel path (same
//      device fns shared; fallback == r13's measured 342us behavior).
// k_layer gather = FROZEN r26 shape (structural floor 55-57.6us across 3
// shapes; r17/r22 window rule holds).

// ---- fp8 helpers (OCP e4m3 on gfx950) ----

__device__ __forceinline__ uint2 pack_fp8x8(const float* v) {
    int lo = 0, hi = 0;
    lo = __builtin_amdgcn_cvt_pk_fp8_f32(v[0], v[1], lo, false);
    lo = __builtin_amdgcn_cvt_pk_fp8_f32(v[2], v[3], lo, true);
    hi = __builtin_amdgcn_cvt_pk_fp8_f32(v[4], v[5], hi, false);
    hi = __builtin_amdgcn_cvt_pk_fp8_f32(v[6], v[7], hi, true);
    return (uint2){(unsigned)lo, (unsigned)hi};
}

__device__ __forceinline__ void acc_fp8x16(uint4 u, f32x2* a2) {
    a2[0] += __builtin_amdgcn_cvt_pk_f32_fp8((int)u.x, false);
    a2[1] += __builtin_amdgcn_cvt_pk_f32_fp8((int)u.x, true);
    a2[2] += __builtin_amdgcn_cvt_pk_f32_fp8((int)u.y, false);
    a2[3] += __builtin_amdgcn_cvt_pk_f32_fp8((int)u.y, true);
    a2[4] += __builtin_amdgcn_cvt_pk_f32_fp8((int)u.z, false);
    a2[5] += __builtin_amdgcn_cvt_pk_f32_fp8((int)u.z, true);
    a2[6] += __builtin_amdgcn_cvt_pk_f32_fp8((int)u.w, false);
    a2[7] += __builtin_amdgcn_cvt_pk_f32_fp8((int)u.w, true);
}

struct GParams {
    const float* x; const int* src; const int* dst; const int* batch;
    const float* We; const float* be; const float* Wg; const float* bg;
    const float* gamma; const float* beta; const float* Wout; const float* bout;
    float* out;
    _Float16* hh0; _Float16* hh1; uint2* hp0; uint2* hp1;
    _Float16* Wp; float* dis; int* rps; int* rpe; int* col;
    unsigned int* ebuf; int* bfill; int* gstart; int* gend;
};

// ---------------- phase A item: prep | range | bscatter | embed ----------------

__device__ __forceinline__ void front_item(const GParams& p, char* smem, int it, int t) {
    if (it < PREP_B) {
        int i = it * 256 + t;
        if (i < NG) p.out[i] = p.bout[0];
        int lane = i & 63;
        int idx = i >> 6;
        int nt = idx & 7;
        int ks = (idx >> 3) & 3;
        int l = idx >> 5;
        int q = lane >> 4, l15 = lane & 15;
        const float* Wl = p.Wg + (size_t)l * H * H;
        _Float16* o = p.Wp + (size_t)idx * 512 + lane * 8;
#pragma unroll
        for (int j = 0; j < 8; j++)
            o[j] = (_Float16)(Wl[(ks * 32 + q * 8 + j) * H + nt * 16 + l15]);
    } else if (it < PREP_B + RANGE_B) {
        int n = (it - PREP_B) * 256 + t;
        if (n < NN) {
            int g = p.batch[n];
            if (n == 0) {
                p.gstart[g] = 0;
            } else {
                int gp = p.batch[n - 1];
                if (gp != g) { p.gstart[g] = n; p.gend[gp] = n; }
            }
            if (n == NN - 1) p.gend[g] = NN;
        }
    } else if (it < PREP_B + RANGE_B + NBB) {
        int* lc = (int*)smem;
        int* lbase = (int*)smem + NBKT;
        for (int i = t; i < NBKT; i += 256) lc[i] = 0;
        __syncthreads();
        int base = (it - PREP_B - RANGE_B) * EPB;
        int rank[8];
        int bk[8];
        unsigned pk[8];
#pragma unroll
        for (int i = 0; i < 8; i++) {
            int e = base + i * 256 + t;
            if (e < NE) {
                int d = p.dst[e];
                int s = p.src[e];
                int b = d >> 8;
                bk[i] = b;
                pk[i] = (unsigned)s | ((unsigned)(d & 255) << 17);
                rank[i] = atomicAdd(&lc[b], 1);
            } else bk[i] = -1;
        }
        __syncthreads();
        for (int i = t; i < NBKT; i += 256)
            lbase[i] = i * CAP + (lc[i] ? atomicAdd(&p.bfill[i], lc[i]) : 0);
        __syncthreads();
#pragma unroll
        for (int i = 0; i < 8; i++) {
            if (bk[i] >= 0)
                p.ebuf[lbase[bk[i]] + rank[i]] = pk[i];
        }
    } else {
        int eb = it - PREP_B - RANGE_B - NBB;
        float* Ws = (float*)smem;                 // 5632 B
        float* bs = (float*)smem + DIM0 * H;      // 512 B
        float* xs = (float*)smem + DIM0 * H + H;  // 704 B
        for (int i = t; i < DIM0 * H; i += 256) Ws[i] = p.We[i];
        if (t < H) bs[t] = p.be[t];
        if (t < 16 * DIM0) xs[t] = p.x[(size_t)eb * (16 * DIM0) + t];
        __syncthreads();
        int nl = t >> 4;
        int node = eb * 16 + nl;
        int l4 = t & 15;
        f16x8 o;
#pragma unroll
        for (int j = 0; j < 8; j++) {
            int c = l4 * 8 + j;
            float acc = bs[c];
#pragma unroll
            for (int k = 0; k < DIM0; k++) acc += xs[nl * DIM0 + k] * Ws[k * H + c];
            o[j] = (_Float16)fmaxf(acc, 0.f);
        }
        *(f16x8*)&p.hh0[(size_t)node * H + l4 * 8] = o;
    }
}

// ---------------- phase B item: bcsr sub-block + fp8 hp pack ----------------

__device__ __forceinline__ void bcsr_item(const GParams& p, char* smem, int it, int t) {
    int b = it >> 2;
    int sub = it & 3;
    int cb = b * CAP;
    int base = cb + sub * SUBCAP;
    int ecnt = p.bfill[b];
    int n0 = (b << 8) + (sub << 6);
    int nb2 = min(64, NN - n0);
    if (nb2 <= 0) return;

    int* lcnt = (int*)smem;
    int* lfill = (int*)smem + 64;
    int* tmp = (int*)smem + 128;
    float* dnsh = (float*)smem + 192;

    if (t < 64) { lcnt[t] = 0; lfill[t] = 0; }
    __syncthreads();

    for (int i = t; i < ecnt; i += 256) {
        unsigned pp = p.ebuf[cb + i];
        int dl = (int)(pp >> 17);
        if ((dl >> 6) == sub) atomicAdd(&lcnt[dl & 63], 1);
    }
    __syncthreads();

    int cnt = (t < 64) ? lcnt[t] : 0;
    if (t < nb2) {
        float dnv = rsqrtf((float)(cnt + 1));
        dnsh[t] = dnv;
        p.dis[n0 + t] = dnv;
    }
    if (t < 64) tmp[t] = cnt;
    __syncthreads();
#pragma unroll
    for (int off = 1; off < 64; off <<= 1) {
        int x = (t >= off && t < 64) ? tmp[t - off] : 0;
        __syncthreads();
        if (t < 64) tmp[t] += x;
        __syncthreads();
    }
    if (t < 64) {
        int incl = tmp[t];
        lcnt[t] = incl - cnt;
        if (t < nb2) {
            p.rps[n0 + t] = base + incl - cnt;
            p.rpe[n0 + t] = base + incl;
        }
    }
    __syncthreads();

    for (int i = t; i < ecnt; i += 256) {
        unsigned pp = p.ebuf[cb + i];
        int dl = (int)(pp >> 17);
        if ((dl >> 6) == sub) {
            int j = dl & 63;
            p.col[base + lcnt[j] + atomicAdd(&lfill[j], 1)] = (int)(pp & 0x1FFFFu);
        }
    }

    __syncthreads();
    const f16x8* hh8 = (const f16x8*)p.hh0;
    for (int idx = t; idx < nb2 * 16; idx += 256) {
        int nl = idx >> 4, l4 = idx & 15;
        f16x8 h8 = hh8[(size_t)(n0 + nl) * 16 + l4];
        float dn = dnsh[nl];
        float hv[8];
#pragma unroll
        for (int j = 0; j < 8; j++) hv[j] = (float)h8[j] * dn;
        p.hp0[(size_t)(n0 + nl) * 16 + l4] = pack_fp8x8(hv);
    }
}

// ---------------- layer tile (one wave = 16 nodes; FROZEN r26 gather) ----------------

__device__ __forceinline__ void layer_tile(const GParams& p, _Float16* Lsw,
                                           const _Float16* hin, _Float16* hout,
                                           const uint2* hpin, uint2* hpout,
                                           const _Float16* Wpl, const float* bias,
                                           const float* gamma, const float* beta,
                                           int nbase, int lane, int store_hp) {
    int q = lane >> 4, l4 = lane & 15;
    int l16 = lane & 15;

    int ev0 = p.rps[nbase + l16];
    int ev1 = p.rpe[nbase + l16];
    float dv = p.dis[nbase + l16];

    int g8 = lane >> 3;
    int l8 = lane & 7;
    const uint4* hp4 = (const uint4*)hpin;

#pragma unroll 1
    for (int r = 0; r < 2; r++) {
        int nl = r * 8 + g8;
        int e0 = __shfl(ev0, nl, 64);
        int e1 = __shfl(ev1, nl, 64);
        float dn = __shfl(dv, nl, 64);
        int node = nbase + nl;

        f32x2 a2[8];
#pragma unroll
        for (int j = 0; j < 8; j++) a2[j] = (f32x2){0.f, 0.f};

        uint4 sv = hp4[(size_t)node * 8 + l8];

        int e = e0;
        int pc0 = 0, pc1 = 0;
        if (e < e1) {
            int m = e1 - 1;
            pc0 = p.col[e];
            pc1 = p.col[(e + 1 < e1) ? e + 1 : m];
        }
#pragma unroll 1
        for (; e + 1 < e1; e += 2) {
            int s0 = pc0, s1 = pc1;
            int n0 = e + 2, n1 = e + 3;
            pc0 = p.col[(n0 < e1) ? n0 : e0];
            pc1 = p.col[(n1 < e1) ? n1 : e0];
            uint4 v0 = hp4[(size_t)s0 * 8 + l8];
            uint4 v1 = hp4[(size_t)s1 * 8 + l8];
            acc_fp8x16(v0, a2);
            acc_fp8x16(v1, a2);
        }
        if (e < e1) {
            uint4 v = hp4[(size_t)pc0 * 8 + l8];
            acc_fp8x16(v, a2);
        }
        acc_fp8x16(sv, a2);

        f16x8 o0, o1;
#pragma unroll
        for (int j = 0; j < 4; j++) {
            o0[2 * j]     = (_Float16)(a2[j][0] * dn);
            o0[2 * j + 1] = (_Float16)(a2[j][1] * dn);
            o1[2 * j]     = (_Float16)(a2[4 + j][0] * dn);
            o1[2 * j + 1] = (_Float16)(a2[4 + j][1] * dn);
        }
        *(f16x8*)&Lsw[nl * 136 + l8 * 16] = o0;
        *(f16x8*)&Lsw[nl * 136 + l8 * 16 + 8] = o1;
    }

    f16x8 af[4];
#pragma unroll
    for (int ks = 0; ks < 4; ks++)
        af[ks] = *(const f16x8*)&Lsw[l4 * 136 + ks * 32 + q * 8];

    float bb[8], gm[8], bt[8];
#pragma unroll
    for (int nt = 0; nt < 8; nt++) {
        bb[nt] = bias[nt * 16 + l4];
        gm[nt] = gamma[nt * 16 + l4];
        bt[nt] = beta[nt * 16 + l4];
    }

    const f16x8* wp8 = (const f16x8*)Wpl;
    f32x4 acc[8];
#pragma unroll
    for (int nt = 0; nt < 8; nt++) {
        acc[nt] = (f32x4){0.f, 0.f, 0.f, 0.f};
#pragma unroll
        for (int ks = 0; ks < 4; ks++) {
            f16x8 bf = wp8[(ks * 8 + nt) * 64 + lane];
            acc[nt] = __builtin_amdgcn_mfma_f32_16x16x32_f16(af[ks], bf, acc[nt], 0, 0, 0);
        }
#pragma unroll
        for (int r = 0; r < 4; r++) acc[nt][r] += bb[nt];
    }

    float mu[4], rs[4];
#pragma unroll
    for (int r = 0; r < 4; r++) {
        float s = 0.f;
#pragma unroll
        for (int nt = 0; nt < 8; nt++) s += acc[nt][r];
#pragma unroll
        for (int off = 8; off > 0; off >>= 1) s += __shfl_xor(s, off, 64);
        mu[r] = s * (1.f / 128.f);
    }
#pragma unroll
    for (int r = 0; r < 4; r++) {
        float v = 0.f;
#pragma unroll
        for (int nt = 0; nt < 8; nt++) {
            float d = acc[nt][r] - mu[r];
            v += d * d;
        }
#pragma unroll
        for (int off = 8; off > 0; off >>= 1) v += __shfl_xor(v, off, 64);
        rs[r] = rsqrtf(v * (1.f / 128.f) + EPS);
    }

#pragma unroll
    for (int nt = 0; nt < 8; nt++)
#pragma unroll
        for (int r = 0; r < 4; r++) {
            float o = fmaxf((acc[nt][r] - mu[r]) * rs[r] * gm[nt] + bt[nt], 0.f);
            Lsw[(q * 4 + r) * 136 + nt * 16 + l4] = (_Float16)o;
        }

    const f16x8* hi8 = (const f16x8*)hin;
    f16x8* ho8 = (f16x8*)hout;
    int ck = lane & 15;
    if (store_hp) {
#pragma unroll
        for (int it = 0; it < 4; it++) {
            int c = it * 64 + lane;
            int rr = c >> 4;
            int row = nbase + rr;
            f16x8 ln = *(const f16x8*)&Lsw[rr * 136 + ck * 8];
            f16x8 res = hi8[(size_t)row * 16 + ck];
            float dn2 = __shfl(dv, rr, 64);
            f16x8 o;
            float hv[8];
#pragma unroll
            for (int j = 0; j < 8; j++) {
                float s = (float)ln[j] + (float)res[j];
                o[j] = (_Float16)s;
                hv[j] = s * dn2;
            }
            ho8[(size_t)row * 16 + ck] = o;
            hpout[(size_t)row * 16 + ck] = pack_fp8x8(hv);
        }
    } else {
        float wv[8];
#pragma unroll
        for (int j = 0; j < 8; j++) wv[j] = p.Wout[ck * 8 + j];
        float pv[4];
#pragma unroll
        for (int it = 0; it < 4; it++) {
            int c = it * 64 + lane;
            int rr = c >> 4;
            int row = nbase + rr;
            f16x8 ln = *(const f16x8*)&Lsw[rr * 136 + ck * 8];
            f16x8 res = hi8[(size_t)row * 16 + ck];
            float pp = 0.f;
#pragma unroll
            for (int j = 0; j < 8; j++)
                pp += ((float)ln[j] + (float)res[j]) * wv[j];
            pp += __shfl_xor(pp, 1, 64);
            pp += __shfl_xor(pp, 2, 64);
            pp += __shfl_xor(pp, 4, 64);
            pp += __shfl_xor(pp, 8, 64);
            pv[it] = pp;
        }
        int srcl = (l16 & 3) << 4;
        float s0 = __shfl(pv[0], srcl, 64);
        float s1 = __shfl(pv[1], srcl, 64);
        float s2 = __shfl(pv[2], srcl, 64);
        float s3 = __shfl(pv[3], srcl, 64);
        float v = (l16 < 4) ? s0 : (l16 < 8) ? s1 : (l16 < 12) ? s2 : s3;
        int g = p.batch[nbase + l16];
#pragma unroll
        for (int off = 1; off < 16; off <<= 1) {
            float vn = __shfl(v, lane - off, 64);
            int gn = __shfl(g, lane - off, 64);
            if (l16 >= off && gn == g) v += vn;
        }
        int gnx = __shfl(g, lane + 1, 64);
        if (lane < 16 && ((l16 == 15) || (gnx != g))) {
            float inv = 1.f / (float)max(p.gend[g] - p.gstart[g], 1);
            atomicAdd(&p.out[g], v * inv);
        }
    }
}

// ---------------- mega kernel (cooperative) ----------------

__global__ __launch_bounds__(256, 8) void k_mega(GParams p) {
    __shared__ alignas(16) char smem[4 * 16 * 136 * 2];   // 17408 B, phase-unioned
    cg::grid_group grid = cg::this_grid();
    int bid = blockIdx.x;
    int t = threadIdx.x;

    for (int it = bid; it < NITEMS_A; it += GRID_MEGA) {
        __syncthreads();
        front_item(p, smem, it, t);
    }
    __threadfence();
    grid.sync();
    __threadfence();

    for (int it = bid; it < NITEMS_B; it += GRID_MEGA) {
        __syncthreads();
        bcsr_item(p, smem, it, t);
    }
    __threadfence();
    grid.sync();
    __threadfence();

    int wave = t >> 6;
    int lane = t & 63;
    _Float16* Lsw = (_Float16*)smem + wave * 16 * 136;

#pragma unroll 1
    for (int l = 0; l < NL; l++) {
        const _Float16* hin = (l & 1) ? p.hh1 : p.hh0;
        _Float16* hout = (l & 1) ? p.hh0 : p.hh1;
        const uint2* hpin = (l & 1) ? p.hp1 : p.hp0;
        uint2* hpout = (l & 1) ? p.hp0 : p.hp1;
#pragma unroll 1
        for (int tile = bid; tile < NTILES; tile += GRID_MEGA) {
            int nbase = tile * 64 + wave * 16;
            if (nbase < NN)
                layer_tile(p, Lsw, hin, hout, hpin, hpout,
                           p.Wp + (size_t)l * 4 * 8 * 512,
                           p.bg + l * H, p.gamma + l * H, p.beta + l * H,
                           nbase, lane, (l != NL - 1) ? 1 : 0);
        }
        if (l != NL - 1) {
            __threadfence();
            grid.sync();
            __threadfence();
        }
    }
}

// ---------------- standalone fallback kernels (r13-equivalent path) ----------------

__global__ __launch_bounds__(256) void k_front_s(GParams p) {
    __shared__ alignas(16) char smem[6912];
    front_item(p, smem, blockIdx.x, threadIdx.x);
}

__global__ __launch_bounds__(256) void k_bcsr_s(GParams p) {
    __shared__ alignas(16) char smem[1024];
    bcsr_item(p, smem, blockIdx.x, threadIdx.x);
}

__global__ __launch_bounds__(256, 8) void k_layer_s(GParams p, int l) {
    __shared__ alignas(16) _Float16 Ls[4][16 * 136];
    int t = threadIdx.x;
    int wave = t >> 6;
    int lane = t & 63;
    int nbase = blockIdx.x * 64 + wave * 16;
    if (nbase >= NN) return;
    const _Float16* hin = (l & 1) ? p.hh1 : p.hh0;
    _Float16* hout = (l & 1) ? p.hh0 : p.hh1;
    const uint2* hpin = (l & 1) ? p.hp1 : p.hp0;
    uint2* hpout = (l & 1) ? p.hp0 : p.hp1;
    layer_tile(p, Ls[wave], hin, hout, hpin, hpout,
               p.Wp + (size_t)l * 4 * 8 * 512,
               p.bg + l * H, p.gamma + l * H, p.beta + l * H,
               nbase, lane, (l != NL - 1) ? 1 : 0);
}

// ---------------- launcher ----------------

extern "C" void kernel_launch(void* const* d_in, const int* in_sizes, int n_in,
                              void* d_out, int out_size, void* d_ws, size_t ws_size,
                              hipStream_t stream) {
    char* ws = (char*)d_ws;
    size_t off = 0;
    auto alloc = [&](size_t bytes) -> char* {
        char* p = ws + off;
        off += (bytes + 255) & ~(size_t)255;
        return p;
    };
    _Float16*     hh0  = (_Float16*)alloc((size_t)NN * H * 2);
    _Float16*     hh1  = (_Float16*)alloc((size_t)NN * H * 2);
    uint2*        hp0  = (uint2*)alloc((size_t)NN * H);
    uint2*        hp1  = (uint2*)alloc((size_t)NN * H);
    _Float16*     Wp   = (_Float16*)alloc((size_t)NL * 4 * 8 * 512 * 2);
    float*        dis  = (float*)alloc((size_t)NN * 4);
    int*          rps  = (int*)alloc((size_t)NN * 4);
    int*          rpe  = (int*)alloc((size_t)NN * 4);
    int*          col  = (int*)alloc((size_t)NBKT * CAP * 4);
    unsigned int* ebuf = (unsigned int*)alloc((size_t)NBKT * CAP * 4);
    int*          bfill = (int*)alloc((NBKT + 1) * 4);
    int*   gstart = (int*)alloc((size_t)NG * 4);
    int*   gend   = (int*)alloc((size_t)NG * 4);

    GParams P;
    P.x = (const float*)d_in[0];
    P.src = (const int*)d_in[1];
    P.dst = (const int*)d_in[1] + NE;
    P.batch = (const int*)d_in[2];
    P.We = (const float*)d_in[3];
    P.be = (const float*)d_in[4];
    P.Wg = (const float*)d_in[5];
    P.bg = (const float*)d_in[6];
    P.gamma = (const float*)d_in[7];
    P.beta = (const float*)d_in[8];
    P.Wout = (const float*)d_in[9];
    P.bout = (const float*)d_in[10];
    P.out = (float*)d_out;
    P.hh0 = hh0; P.hh1 = hh1; P.hp0 = hp0; P.hp1 = hp1;
    P.Wp = Wp; P.dis = dis; P.rps = rps; P.rpe = rpe; P.col = col;
    P.ebuf = ebuf; P.bfill = bfill; P.gstart = gstart; P.gend = gend;

    hipMemsetAsync(bfill, 0, (NBKT + 1) * sizeof(int), stream);

    void* kp[] = {&P};
    hipError_t err = hipLaunchCooperativeKernel((const void*)k_mega,
                                                dim3(GRID_MEGA), dim3(256), kp, 0, stream);
    if (err != hipSuccess) {
        (void)hipGetLastError();   // clear sticky error; use proven multi-kernel path
        k_front_s<<<NITEMS_A, 256, 0, stream>>>(P);
        k_bcsr_s<<<NITEMS_B, 256, 0, stream>>>(P);
        for (int l = 0; l < NL; l++)
            k_layer_s<<<NTILES, 256, 0, stream>>>(P, l);
    }
}

// Round 17
// 344.056 us; speedup vs baseline: 6.2070x; 6.2070x over previous
//
#include <hip/hip_runtime.h>

#define NN 100000
#define NE 1600000
#define DIM0 11
#define H 128
#define NL 4
#define NG 4096
#define EPS 1e-5f

#define NBKT 391       // buckets of 256 nodes: bucket = dst >> 8
#define CAP 5120       // fixed bucket capacity
#define SUBCAP 1280    // per-64-node sub-region of col
#define EPB 4096       // edges per block in scatter phase
static constexpr int NBB = (NE + EPB - 1) / EPB;  // 391
#define PREP_B 32
#define RANGE_B 391    // (NN+255)/256
static constexpr int FRONT_B = PREP_B + RANGE_B + NBB + NN / 16;  // 32+391+391+6250

typedef _Float16 f16x8 __attribute__((ext_vector_type(8)));
typedef float f32x4 __attribute__((ext_vector_type(4)));
typedef float f32x2 __attribute__((ext_vector_type(2)));

// r29/r30 post-mortem: cooperative mega-kernel closed after three distinct
// failures (r27 silent launch-reject -> out=0; r28 VGPR=32 spill -> 2070us;
// r29 zero-margin capacity (1024 blocks == exactly 4/CU at VGPR>64) ->
// probable grid.sync deadlock/container timeout). REVERT to the r13-measured
// artifact (342.2us, passed): multi-kernel, frozen r26 gather (8x8-lane
// uint4 groups, 55.2us/layer, FETCH 95.5MB = structural gather floor across
// 3 independent shapes), fused front-end, split bcsr, L3 fused pool with
// segmented wave reduction (~1.7 atomics/wave).

// ---- fp8 helpers (OCP e4m3 on gfx950) ----

__device__ __forceinline__ uint2 pack_fp8x8(const float* v) {
    int lo = 0, hi = 0;
    lo = __builtin_amdgcn_cvt_pk_fp8_f32(v[0], v[1], lo, false);
    lo = __builtin_amdgcn_cvt_pk_fp8_f32(v[2], v[3], lo, true);
    hi = __builtin_amdgcn_cvt_pk_fp8_f32(v[4], v[5], hi, false);
    hi = __builtin_amdgcn_cvt_pk_fp8_f32(v[6], v[7], hi, true);
    return (uint2){(unsigned)lo, (unsigned)hi};
}

__device__ __forceinline__ void acc_fp8x16(uint4 u, f32x2* a2) {
    a2[0] += __builtin_amdgcn_cvt_pk_f32_fp8((int)u.x, false);
    a2[1] += __builtin_amdgcn_cvt_pk_f32_fp8((int)u.x, true);
    a2[2] += __builtin_amdgcn_cvt_pk_f32_fp8((int)u.y, false);
    a2[3] += __builtin_amdgcn_cvt_pk_f32_fp8((int)u.y, true);
    a2[4] += __builtin_amdgcn_cvt_pk_f32_fp8((int)u.z, false);
    a2[5] += __builtin_amdgcn_cvt_pk_f32_fp8((int)u.z, true);
    a2[6] += __builtin_amdgcn_cvt_pk_f32_fp8((int)u.w, false);
    a2[7] += __builtin_amdgcn_cvt_pk_f32_fp8((int)u.w, true);
}

// ---------------- front: Wpack + out-init | range | bscatter | embed-hh ----------------

__global__ __launch_bounds__(256) void k_front(const float* __restrict__ W, _Float16* __restrict__ Wp,
                                               float* __restrict__ out, const float* __restrict__ bout,
                                               const int* __restrict__ batch, int* __restrict__ gstart,
                                               int* __restrict__ gend,
                                               const int* __restrict__ src, const int* __restrict__ dst,
                                               int* __restrict__ bfill, unsigned int* __restrict__ ebuf,
                                               const float* __restrict__ x, const float* __restrict__ We,
                                               const float* __restrict__ be, _Float16* __restrict__ hh) {
    __shared__ int lc[NBKT];
    __shared__ int lbase[NBKT];
    __shared__ float Ws[DIM0 * H];
    __shared__ float bs[H];
    __shared__ float xs[16 * DIM0];
    int bb = blockIdx.x;
    int t = threadIdx.x;

    if (bb < PREP_B) {
        // ---- prep: out init + W pack (8192 threads) ----
        int i = bb * 256 + t;
        if (i < NG) out[i] = bout[0];
        int lane = i & 63;
        int idx = i >> 6;          // 0..127
        int nt = idx & 7;
        int ks = (idx >> 3) & 3;
        int l = idx >> 5;
        int q = lane >> 4, l15 = lane & 15;
        const float* Wl = W + (size_t)l * H * H;
        _Float16* o = Wp + (size_t)idx * 512 + lane * 8;
#pragma unroll
        for (int j = 0; j < 8; j++)
            o[j] = (_Float16)(Wl[(ks * 32 + q * 8 + j) * H + nt * 16 + l15]);
    } else if (bb < PREP_B + RANGE_B) {
        // ---- range: batch sorted -> boundary stores, no atomics ----
        int n = (bb - PREP_B) * 256 + t;
        if (n < NN) {
            int g = batch[n];
            if (n == 0) {
                gstart[g] = 0;
            } else {
                int gp = batch[n - 1];
                if (gp != g) { gstart[g] = n; gend[gp] = n; }
            }
            if (n == NN - 1) gend[g] = NN;
        }
    } else if (bb < PREP_B + RANGE_B + NBB) {
        // ---- bscatter (EPB 4096, 16 edges/thread) ----
        for (int i = t; i < NBKT; i += 256) lc[i] = 0;
        __syncthreads();
        int base = (bb - PREP_B - RANGE_B) * EPB;
        int rank[16];
        int bk[16];
        unsigned pk[16];
#pragma unroll
        for (int i = 0; i < 16; i++) {
            int e = base + i * 256 + t;
            if (e < NE) {
                int d = dst[e];
                int s = src[e];
                int b = d >> 8;
                bk[i] = b;
                pk[i] = (unsigned)s | ((unsigned)(d & 255) << 17);
                rank[i] = atomicAdd(&lc[b], 1);
            } else bk[i] = -1;
        }
        __syncthreads();
        for (int i = t; i < NBKT; i += 256)
            lbase[i] = i * CAP + (lc[i] ? atomicAdd(&bfill[i], lc[i]) : 0);
        __syncthreads();
#pragma unroll
        for (int i = 0; i < 16; i++) {
            if (bk[i] >= 0)
                ebuf[lbase[bk[i]] + rank[i]] = pk[i];
        }
    } else {
        // ---- embed: hh = fp16(relu(x @ We + be)) only (no dis dependency) ----
        int eb = bb - PREP_B - RANGE_B - NBB;
        for (int i = t; i < DIM0 * H; i += 256) Ws[i] = We[i];
        if (t < H) bs[t] = be[t];
        if (t < 16 * DIM0) xs[t] = x[(size_t)eb * (16 * DIM0) + t];
        __syncthreads();
        int nl = t >> 4;
        int node = eb * 16 + nl;
        int l4 = t & 15;
        f16x8 o;
#pragma unroll
        for (int j = 0; j < 8; j++) {
            int c = l4 * 8 + j;
            float acc = bs[c];
#pragma unroll
            for (int k = 0; k < DIM0; k++) acc += xs[nl * DIM0 + k] * Ws[k * H + c];
            o[j] = (_Float16)fmaxf(acc, 0.f);
        }
        *(f16x8*)&hh[(size_t)node * H + l4 * 8] = o;
    }
}

// ---------------- CSR pass 2 + fp8 hp pack: 4 sub-blocks per bucket ----------------

__global__ __launch_bounds__(256) void k_bcsr(const unsigned int* __restrict__ ebuf,
                                              const int* __restrict__ bfill,
                                              int* __restrict__ rps, int* __restrict__ rpe,
                                              int* __restrict__ col, float* __restrict__ dis,
                                              const _Float16* __restrict__ hh, uint2* __restrict__ hp) {
    __shared__ int lcnt[64];
    __shared__ int lfill[64];
    __shared__ int tmp[64];
    __shared__ float dnsh[64];
    int t = threadIdx.x;
    int b = blockIdx.x >> 2;        // bucket
    int sub = blockIdx.x & 3;       // 64-node sub-range
    int cb = b * CAP;
    int base = cb + sub * SUBCAP;   // private col region
    int ecnt = bfill[b];
    int n0 = (b << 8) + (sub << 6);
    int nb2 = min(64, NN - n0);
    if (nb2 <= 0) return;           // uniform per block

    if (t < 64) { lcnt[t] = 0; lfill[t] = 0; }
    __syncthreads();

    for (int i = t; i < ecnt; i += 256) {
        unsigned p = ebuf[cb + i];
        int dl = (int)(p >> 17);
        if ((dl >> 6) == sub) atomicAdd(&lcnt[dl & 63], 1);
    }
    __syncthreads();

    int cnt = (t < 64) ? lcnt[t] : 0;
    if (t < nb2) {
        float dnv = rsqrtf((float)(cnt + 1));
        dnsh[t] = dnv;
        dis[n0 + t] = dnv;
    }
    if (t < 64) tmp[t] = cnt;
    __syncthreads();
#pragma unroll
    for (int off = 1; off < 64; off <<= 1) {
        int x = (t >= off && t < 64) ? tmp[t - off] : 0;
        __syncthreads();
        if (t < 64) tmp[t] += x;
        __syncthreads();
    }
    if (t < 64) {
        int incl = tmp[t];
        lcnt[t] = incl - cnt;       // exclusive prefix (scatter offsets)
        if (t < nb2) {
            rps[n0 + t] = base + incl - cnt;
            rpe[n0 + t] = base + incl;
        }
    }
    __syncthreads();

    for (int i = t; i < ecnt; i += 256) {
        unsigned p = ebuf[cb + i];
        int dl = (int)(p >> 17);
        if ((dl >> 6) == sub) {
            int j = dl & 63;
            col[base + lcnt[j] + atomicAdd(&lfill[j], 1)] = (int)(p & 0x1FFFFu);
        }
    }

    __syncthreads();
    // fp8 pre-scaled gather copy for this sub-block's nodes
    const f16x8* hh8 = (const f16x8*)hh;
    for (int idx = t; idx < nb2 * 16; idx += 256) {
        int nl = idx >> 4, l4 = idx & 15;
        f16x8 h8 = hh8[(size_t)(n0 + nl) * 16 + l4];
        float dn = dnsh[nl];
        float hv[8];
#pragma unroll
        for (int j = 0; j < 8; j++) hv[j] = (float)h8[j] * dn;
        hp[(size_t)(n0 + nl) * 16 + l4] = pack_fp8x8(hv);
    }
}

// ---------------- fused layer: hout = relu(LN(agg(hin) @ W + b)) + hin ----------------
// Phase 1 (FROZEN r26): 8x8-lane groups; group owns a node (2 rounds x 8
// nodes); lane loads uint4 -> one instruction = 8 rows (1KB). Phase 2 MFMA +
// LN. Mode 1: store hout + fp8 copy. Mode 0 (last layer): fused mean-pool
// via segmented wave reduction (sorted batch -> ascending g).

__global__ __launch_bounds__(128, 6) void k_layer(const _Float16* __restrict__ hin,
                                                  _Float16* __restrict__ hout,
                                                  const uint2* __restrict__ hpin,
                                                  uint2* __restrict__ hpout,
                                                  const float* __restrict__ dis, const int* __restrict__ rps,
                                                  const int* __restrict__ rpe, const int* __restrict__ col,
                                                  const _Float16* __restrict__ Wp,
                                                  const float* __restrict__ bias,
                                                  const float* __restrict__ gamma,
                                                  const float* __restrict__ beta,
                                                  const int* __restrict__ batch,
                                                  const int* __restrict__ gstart,
                                                  const int* __restrict__ gend,
                                                  const float* __restrict__ Wout,
                                                  float* __restrict__ out,
                                                  int store_hp) {
    __shared__ _Float16 Ls[2][16][136];   // 8704 B
    int tid = threadIdx.x;
    int wave = tid >> 6;
    int lane = tid & 63;
    int q = lane >> 4, l4 = lane & 15;
    int nbase = blockIdx.x * 32 + wave * 16;   // 32 | NN, no tail

    // wave-wide prefetch of the 16 nodes' CSR ranges + dis
    int l16 = lane & 15;
    int ev0 = rps[nbase + l16];
    int ev1 = rpe[nbase + l16];
    float dv = dis[nbase + l16];

    // ---- phase 1: gather 16 nodes into Ls, 8 nodes per round ----
    int g8 = lane >> 3;     // group 0..7 (owns one node per round)
    int l8 = lane & 7;      // lane in group: row bytes [l8*16, +16)
    const uint4* hp4 = (const uint4*)hpin;

#pragma unroll 1
    for (int r = 0; r < 2; r++) {
        int nl = r * 8 + g8;
        int e0 = __shfl(ev0, nl, 64);
        int e1 = __shfl(ev1, nl, 64);
        float dn = __shfl(dv, nl, 64);
        int node = nbase + nl;

        f32x2 a2[8];
#pragma unroll
        for (int j = 0; j < 8; j++) a2[j] = (f32x2){0.f, 0.f};

        uint4 sv = hp4[(size_t)node * 8 + l8];   // self row, issued early

        int e = e0;
        int pc0 = 0, pc1 = 0;
        if (e < e1) {                       // prime col pipeline (clamped)
            int m = e1 - 1;
            pc0 = col[e];
            pc1 = col[(e + 1 < e1) ? e + 1 : m];
        }
#pragma unroll 1
        for (; e + 1 < e1; e += 2) {
            int s0 = pc0, s1 = pc1;
            int n0 = e + 2, n1 = e + 3;
            pc0 = col[(n0 < e1) ? n0 : e0];   // next-iter cols overlap row loads
            pc1 = col[(n1 < e1) ? n1 : e0];
            uint4 v0 = hp4[(size_t)s0 * 8 + l8];
            uint4 v1 = hp4[(size_t)s1 * 8 + l8];
            acc_fp8x16(v0, a2);
            acc_fp8x16(v1, a2);
        }
        if (e < e1) {   // tail (1 edge): col already prefetched
            uint4 v = hp4[(size_t)pc0 * 8 + l8];
            acc_fp8x16(v, a2);
        }
        acc_fp8x16(sv, a2);   // self-loop

        f16x8 o0, o1;
#pragma unroll
        for (int j = 0; j < 4; j++) {
            o0[2 * j]     = (_Float16)(a2[j][0] * dn);
            o0[2 * j + 1] = (_Float16)(a2[j][1] * dn);
            o1[2 * j]     = (_Float16)(a2[4 + j][0] * dn);
            o1[2 * j + 1] = (_Float16)(a2[4 + j][1] * dn);
        }
        *(f16x8*)&Ls[wave][nl][l8 * 16] = o0;
        *(f16x8*)&Ls[wave][nl][l8 * 16 + 8] = o1;
    }

    // ---- phase 2: read A-fragments into registers, then GEMM + LN (Ls reused) ----
    f16x8 af[4];
#pragma unroll
    for (int ks = 0; ks < 4; ks++)
        af[ks] = *(const f16x8*)&Ls[wave][l4][ks * 32 + q * 8];

    float bb[8], gm[8], bt[8];
#pragma unroll
    for (int nt = 0; nt < 8; nt++) {
        bb[nt] = bias[nt * 16 + l4];
        gm[nt] = gamma[nt * 16 + l4];
        bt[nt] = beta[nt * 16 + l4];
    }

    const f16x8* wp8 = (const f16x8*)Wp;
    f32x4 acc[8];
#pragma unroll
    for (int nt = 0; nt < 8; nt++) {
        acc[nt] = (f32x4){0.f, 0.f, 0.f, 0.f};
#pragma unroll
        for (int ks = 0; ks < 4; ks++) {
            f16x8 bf = wp8[(ks * 8 + nt) * 64 + lane];
            acc[nt] = __builtin_amdgcn_mfma_f32_16x16x32_f16(af[ks], bf, acc[nt], 0, 0, 0);
        }
#pragma unroll
        for (int r = 0; r < 4; r++) acc[nt][r] += bb[nt];
    }

    float mu[4], rs[4];
#pragma unroll
    for (int r = 0; r < 4; r++) {
        float s = 0.f;
#pragma unroll
        for (int nt = 0; nt < 8; nt++) s += acc[nt][r];
#pragma unroll
        for (int off = 8; off > 0; off >>= 1) s += __shfl_xor(s, off, 64);
        mu[r] = s * (1.f / 128.f);
    }
#pragma unroll
    for (int r = 0; r < 4; r++) {
        float v = 0.f;
#pragma unroll
        for (int nt = 0; nt < 8; nt++) {
            float d = acc[nt][r] - mu[r];
            v += d * d;
        }
#pragma unroll
        for (int off = 8; off > 0; off >>= 1) v += __shfl_xor(v, off, 64);
        rs[r] = rsqrtf(v * (1.f / 128.f) + EPS);
    }

    // overwrite Ls with LN output (af already in registers)
#pragma unroll
    for (int nt = 0; nt < 8; nt++)
#pragma unroll
        for (int r = 0; r < 4; r++) {
            float o = fmaxf((acc[nt][r] - mu[r]) * rs[r] * gm[nt] + bt[nt], 0.f);
            Ls[wave][q * 4 + r][nt * 16 + l4] = (_Float16)o;
        }

    // epilogue
    const f16x8* hi8 = (const f16x8*)hin;
    f16x8* ho8 = (f16x8*)hout;
    int ck = lane & 15;
    if (store_hp) {
#pragma unroll
        for (int it = 0; it < 4; it++) {
            int c = it * 64 + lane;
            int rr = c >> 4;
            int row = nbase + rr;
            f16x8 ln = *(const f16x8*)&Ls[wave][rr][ck * 8];
            f16x8 res = hi8[(size_t)row * 16 + ck];
            float dn2 = __shfl(dv, rr, 64);
            f16x8 o;
            float hv[8];
#pragma unroll
            for (int j = 0; j < 8; j++) {
                float s = (float)ln[j] + (float)res[j];
                o[j] = (_Float16)s;
                hv[j] = s * dn2;
            }
            ho8[(size_t)row * 16 + ck] = o;
            hpout[(size_t)row * 16 + ck] = pack_fp8x8(hv);
        }
    } else {
        // fused global-mean-pool with segmented wave reduction
        float wv[8];
#pragma unroll
        for (int j = 0; j < 8; j++) wv[j] = Wout[ck * 8 + j];
        float pv[4];
#pragma unroll
        for (int it = 0; it < 4; it++) {
            int c = it * 64 + lane;
            int rr = c >> 4;
            int row = nbase + rr;
            f16x8 ln = *(const f16x8*)&Ls[wave][rr][ck * 8];
            f16x8 res = hi8[(size_t)row * 16 + ck];
            float p = 0.f;
#pragma unroll
            for (int j = 0; j < 8; j++)
                p += ((float)ln[j] + (float)res[j]) * wv[j];
            p += __shfl_xor(p, 1, 64);
            p += __shfl_xor(p, 2, 64);
            p += __shfl_xor(p, 4, 64);
            p += __shfl_xor(p, 8, 64);
            pv[it] = p;   // replicated across the 16-lane quarter
        }
        // redistribute: lane l16 takes row l16's value (src lane (l16&3)*16, slot l16>>2)
        int srcl = (l16 & 3) << 4;
        float s0 = __shfl(pv[0], srcl, 64);
        float s1 = __shfl(pv[1], srcl, 64);
        float s2 = __shfl(pv[2], srcl, 64);
        float s3 = __shfl(pv[3], srcl, 64);
        float v = (l16 < 4) ? s0 : (l16 < 8) ? s1 : (l16 < 12) ? s2 : s3;
        int g = batch[nbase + l16];
        // segmented inclusive sum (g ascending over rows; 16-lane groups)
#pragma unroll
        for (int off = 1; off < 16; off <<= 1) {
            float vn = __shfl(v, lane - off, 64);
            int gn = __shfl(g, lane - off, 64);
            if (l16 >= off && gn == g) v += vn;
        }
        int gnx = __shfl(g, lane + 1, 64);
        if (lane < 16 && ((l16 == 15) || (gnx != g))) {
            float inv = 1.f / (float)max(gend[g] - gstart[g], 1);
            atomicAdd(&out[g], v * inv);
        }
    }
}

// ---------------- launcher ----------------

extern "C" void kernel_launch(void* const* d_in, const int* in_sizes, int n_in,
                              void* d_out, int out_size, void* d_ws, size_t ws_size,
                              hipStream_t stream) {
    const float* x       = (const float*)d_in[0];
    const int*   edge    = (const int*)d_in[1];
    const int*   batch   = (const int*)d_in[2];
    const float* W_embed = (const float*)d_in[3];
    const float* b_embed = (const float*)d_in[4];
    const float* W_gnn   = (const float*)d_in[5];
    const float* b_gnn   = (const float*)d_in[6];
    const float* gamma   = (const float*)d_in[7];
    const float* beta    = (const float*)d_in[8];
    const float* W_out   = (const float*)d_in[9];
    const float* b_out   = (const float*)d_in[10];
    float* out = (float*)d_out;

    char* ws = (char*)d_ws;
    size_t off = 0;
    auto alloc = [&](size_t bytes) -> char* {
        char* p = ws + off;
        off += (bytes + 255) & ~(size_t)255;
        return p;
    };
    _Float16*     hh0  = (_Float16*)alloc((size_t)NN * H * 2);
    _Float16*     hh1  = (_Float16*)alloc((size_t)NN * H * 2);
    uint2*        hp0  = (uint2*)alloc((size_t)NN * H);       // fp8 gather copies
    uint2*        hp1  = (uint2*)alloc((size_t)NN * H);
    _Float16*     Wp   = (_Float16*)alloc((size_t)NL * 4 * 8 * 512 * 2);
    float*        dis  = (float*)alloc((size_t)NN * 4);
    int*          rps  = (int*)alloc((size_t)NN * 4);
    int*          rpe  = (int*)alloc((size_t)NN * 4);
    int*          col  = (int*)alloc((size_t)NBKT * CAP * 4);
    unsigned int* ebuf = (unsigned int*)alloc((size_t)NBKT * CAP * 4);
    int*          bfill = (int*)alloc((NBKT + 1) * 4);
    int*   gstart = (int*)alloc((size_t)NG * 4);
    int*   gend   = (int*)alloc((size_t)NG * 4);

    const int* srcp = edge;
    const int* dstp = edge + NE;

    hipMemsetAsync(bfill, 0, (NBKT + 1) * sizeof(int), stream);
    k_front<<<FRONT_B, 256, 0, stream>>>(W_gnn, Wp, out, b_out,
                                         batch, gstart, gend,
                                         srcp, dstp, bfill, ebuf,
                                         x, W_embed, b_embed, hh0);
    k_bcsr<<<NBKT * 4, 256, 0, stream>>>(ebuf, bfill, rps, rpe, col, dis, hh0, hp0);

    // ping-pong: L0 hh0->hh1, L1 hh1->hh0, L2 hh0->hh1, L3 fused-pool -> out
    _Float16* hb[2] = {hh0, hh1};
    uint2*    hp[2] = {hp0, hp1};
    for (int l = 0; l < NL; l++) {
        k_layer<<<(NN + 31) / 32, 128, 0, stream>>>(hb[l & 1], hb[(l & 1) ^ 1],
                                                    hp[l & 1], hp[(l & 1) ^ 1],
                                                    dis, rps, rpe, col,
                                                    Wp + (size_t)l * 4 * 8 * 512,
                                                    b_gnn + l * H, gamma + l * H, beta + l * H,
                                                    batch, gstart, gend, W_out, out,
                                                    (l != NL - 1) ? 1 : 0);
    }
}